// Round 9
// baseline (77.079 us; speedup 1.0000x reference)
//
#include <hip/hip_runtime.h>
#include <math.h>

typedef _Float16 f16x8 __attribute__((ext_vector_type(8)));
typedef _Float16 f16x2 __attribute__((ext_vector_type(2)));
typedef float    f32x4 __attribute__((ext_vector_type(4)));

union F16x8u { f16x8 v; f16x2 h[4]; };

// v_sin_f32 / v_cos_f32 take REVOLUTIONS: sin(2*pi*x) = v_sin(x).
__device__ __forceinline__ float cos1_hw(float x) { return __builtin_amdgcn_cosf(x); }
__device__ __forceinline__ float sin1_hw(float x) { return __builtin_amdgcn_sinf(x); }

// v_cvt_pkrtz_f16_f32 returns a __fp16 vector; bit-cast to our _Float16 pair.
__device__ __forceinline__ f16x2 pkrtz(float a, float b)
{
    return __builtin_bit_cast(f16x2, __builtin_amdgcn_cvt_pkrtz(a, b));
}

// Packed complex rotation: v=(er,ei) -> v*e^{i phi} with cc=(c,c), ns=(-s,s).
// Compiles to 2 VOP3P ops (v_pk_mul_f16 + v_pk_fma_f16, swap via op_sel).
__device__ __forceinline__ f16x2 pkrot(f16x2 v, f16x2 cc, f16x2 ns)
{
    const f16x2 sw = __builtin_shufflevector(v, v, 1, 0);
    return v * cc + sw * ns;
}

// red += a.x*b.x + a.y*b.y  (v_dot2_f32_f16 when available)
#if __has_builtin(__builtin_amdgcn_fdot2)
typedef __fp16 hh2 __attribute__((ext_vector_type(2)));
__device__ __forceinline__ float fdot2(f16x2 a, f16x2 b, float c)
{
    return __builtin_amdgcn_fdot2(__builtin_bit_cast(hh2, a),
                                  __builtin_bit_cast(hh2, b), c, false);
}
#else
__device__ __forceinline__ float fdot2(f16x2 a, f16x2 b, float c)
{
    return fmaf((float)a[1], (float)b[1], fmaf((float)a[0], (float)b[0], c));
}
#endif

// ---------------------------------------------------------------------------
// ROUND 15 = PACKED-F16 INTERP.
// r14 landed: MFMA-DFT saved 22.7us (kernel 54.3 -> ~31.6, anchor F+L=45.2
// measured from r7's profiled 54.3). r7 counters: interp stage is VALU-issue
// bound (~12us busy + ~36% stalls); occupancy capped at 16 waves/CU by the
// 128-reg wave footprint (64 VGPR + 64 AGPR A-frags) -- grid scaling can't
// help. Conj-symmetry fold rejected: k=32 Nyquist row breaks G[p,-m]=conj,
// correction is another per-point 31-dot.
// This round cuts interp VALU ~25-30%:
//   * E1 rotation chains in packed f16 (v_pk_fma_f16): 2 ops/rot-step vs 4-5,
//     no per-jp pkrtz (repack = 2 shuffles + 1 negate).
//   * stage-B apply via v_dot2_f32_f16 (__has_builtin-guarded) + pk-rotated
//     seed phases b0..b3.
// DFT + staging + hoist byte-identical to r14. Grid 256 x 1024 unchanged.
// ---------------------------------------------------------------------------

__global__ __launch_bounds__(1024, 4)
void fourier_fused(const float* __restrict__ y,
                   const float* __restrict__ xnew,
                   float* __restrict__ out)
{
    __shared__ _Float16 Yt [64 * 72];    // Y^T f16: Yt[n2][n1], pitch 72
    __shared__ _Float16 Trl[64 * 72];    // T re: Trl[k][n2]
    __shared__ _Float16 Til[64 * 72];    // T im
    __shared__ _Float16 FrL[64 * 72];    // F^T re: FrL[m][k]
    __shared__ _Float16 FiL[64 * 72];    // F^T im
    __shared__ float2   XY[2048];        // sample coords
    __shared__ float2   tw[64];          // (cos, sin)(2pi n/64)

    const int tid   = threadIdx.x;
    const int batch = blockIdx.x >> 3;
    const int sgrp  = blockIdx.x & 7;                 // 8 blocks per batch
    const int pbase = (batch << 14) + (sgrp << 11);   // 2048 points

    // ---- stage xnew + y (transposed f16) + twiddles ----
    ((float4*)XY)[tid] = ((const float4*)(xnew + ((size_t)pbase << 1)))[tid];
    {
        const float4 v = ((const float4*)(y + (batch << 12)))[tid];
        const int n1 = tid >> 4;            // row of y
        const int n2 = (tid & 15) << 2;     // col base
        Yt[(n2 + 0) * 72 + n1] = (_Float16)v.x;
        Yt[(n2 + 1) * 72 + n1] = (_Float16)v.y;
        Yt[(n2 + 2) * 72 + n1] = (_Float16)v.z;
        Yt[(n2 + 3) * 72 + n1] = (_Float16)v.w;
    }
    if (tid < 64) {
        const float a = (float)tid * (1.0f / 64.0f);
        tw[tid] = make_float2(cos1_hw(a), sin1_hw(a));
    }
    __syncthreads();

    const int lane = tid & 63;
    const int wv   = tid >> 6;           // 0..15
    const int quad = lane >> 4;
    const int lrow = lane & 15;

    // ---- DFT pass A (MFMA): T[k][n2] = sum_n1 e^{-2pi i k n1/64} Y[n1][n2]
    {
        const int rt   = wv >> 2;
        const int ct   = wv & 3;
        const int krow = (rt << 4) + lrow;
        f32x4 Tr = (f32x4){0.f, 0.f, 0.f, 0.f};
        f32x4 Ti = (f32x4){0.f, 0.f, 0.f, 0.f};
#pragma unroll
        for (int kt = 0; kt < 2; ++kt) {
            const int n1b = (kt << 5) + (quad << 3);
            F16x8u cf, sn;                      // cos, -sin  (W = c - i s)
#pragma unroll
            for (int jp = 0; jp < 4; ++jp) {
                const float2 wa = tw[(krow * (n1b + 2 * jp    )) & 63];
                const float2 wb = tw[(krow * (n1b + 2 * jp + 1)) & 63];
                cf.h[jp] = pkrtz(wa.x, wb.x);
                sn.h[jp] = pkrtz(-wa.y, -wb.y);
            }
            const f16x8 yf = *(const f16x8*)&Yt[((ct << 4) + lrow) * 72 + n1b];
            Tr = __builtin_amdgcn_mfma_f32_16x16x32_f16(cf.v, yf, Tr, 0, 0, 0);
            Ti = __builtin_amdgcn_mfma_f32_16x16x32_f16(sn.v, yf, Ti, 0, 0, 0);
        }
#pragma unroll
        for (int reg = 0; reg < 4; ++reg) {
            const int k = (rt << 4) + (quad << 2) + reg;
            Trl[k * 72 + (ct << 4) + lrow] = (_Float16)Tr[reg];
            Til[k * 72 + (ct << 4) + lrow] = (_Float16)Ti[reg];
        }
    }
    __syncthreads();

    // ---- DFT pass B (MFMA): F^T[m][k] = sum_n2 W2[m][n2] T^T[n2][k] ----
    {
        const int mt2 = wv >> 2;
        const int ct2 = wv & 3;
        const int mrow = (mt2 << 4) + lrow;
        f32x4 Fr = (f32x4){0.f, 0.f, 0.f, 0.f};
        f32x4 Fi = (f32x4){0.f, 0.f, 0.f, 0.f};
#pragma unroll
        for (int kt = 0; kt < 2; ++kt) {
            const int n2b = (kt << 5) + (quad << 3);
            F16x8u cf, sf, sn;
#pragma unroll
            for (int jp = 0; jp < 4; ++jp) {
                const float2 wa = tw[(mrow * (n2b + 2 * jp    )) & 63];
                const float2 wb = tw[(mrow * (n2b + 2 * jp + 1)) & 63];
                cf.h[jp] = pkrtz(wa.x, wb.x);
                sf.h[jp] = pkrtz(wa.y, wb.y);
                sn.h[jp] = pkrtz(-wa.y, -wb.y);
            }
            const f16x8 btr = *(const f16x8*)&Trl[((ct2 << 4) + lrow) * 72 + n2b];
            const f16x8 bti = *(const f16x8*)&Til[((ct2 << 4) + lrow) * 72 + n2b];
            Fr = __builtin_amdgcn_mfma_f32_16x16x32_f16(cf.v, btr, Fr, 0, 0, 0);
            Fr = __builtin_amdgcn_mfma_f32_16x16x32_f16(sf.v, bti, Fr, 0, 0, 0);
            Fi = __builtin_amdgcn_mfma_f32_16x16x32_f16(cf.v, bti, Fi, 0, 0, 0);
            Fi = __builtin_amdgcn_mfma_f32_16x16x32_f16(sn.v, btr, Fi, 0, 0, 0);
        }
#pragma unroll
        for (int reg = 0; reg < 4; ++reg) {
            const int m = (mt2 << 4) + (quad << 2) + reg;
            FrL[m * 72 + (ct2 << 4) + lrow] = (_Float16)Fr[reg];
            FiL[m * 72 + (ct2 << 4) + lrow] = (_Float16)Fi[reg];
        }
    }
    __syncthreads();

    // ---- hoist A-operand (F^T) fragments once per wave ----
    f16x8 Ar[4][2], Ai[4][2];
#pragma unroll
    for (int nt = 0; nt < 4; ++nt)
#pragma unroll
        for (int kt = 0; kt < 2; ++kt) {
            const int off = ((nt << 4) + lrow) * 72 + (kt << 5) + (quad << 3);
            Ar[nt][kt] = *(const f16x8*)&FrL[off];
            Ai[nt][kt] = *(const f16x8*)&FiL[off];
        }

    // ---- interp: G[p,m] = sum_k F[k,m] E1[p,k] (MFMA);
    //      red = Re sum_m G[p,m] E2[p,m] (packed f16 + fdot2) ----
#pragma unroll 1
    for (int mt = 0; mt < 8; ++mt) {
        const int lpt = ((mt >> 1) << 9) + (wv << 5) + ((mt & 1) << 4);
        const float2 xv = XY[lpt + lrow];

        // rotation steps e^{2pi i x1} (f32 seed step) and e^{2pi i 2 x1} (pk)
        const float cs1 = cos1_hw(xv.x);
        const float sn1 = sin1_hw(xv.x);
        const float cs1b = fmaf(cs1, cs1, -(sn1 * sn1));
        const float sn1b = 2.0f * cs1 * sn1;
        const f16x2 cc2 = pkrtz(cs1b, cs1b);
        const f16x2 ns2 = pkrtz(-sn1b, sn1b);

        f32x4 Gr[4], Gi[4];
#pragma unroll
        for (int nt = 0; nt < 4; ++nt) {
            Gr[nt] = (f32x4){0.f, 0.f, 0.f, 0.f};
            Gi[nt] = (f32x4){0.f, 0.f, 0.f, 0.f};
        }

#pragma unroll
        for (int kt = 0; kt < 2; ++kt) {
            // base frequency of this lane's 8-k run (never crosses k=32)
            const float fb = (float)((quad << 3) - (kt ? 32 : 0));
            float th = xv.x * fb;
            th -= floorf(th);                      // revolutions in [0,1)
            const float er0f = cos1_hw(th);
            const float ei0f = sin1_hw(th);
            const float er1f = fmaf(-ei0f, sn1, er0f * cs1);
            const float ei1f = fmaf( er0f, sn1, ei0f * cs1);
            // two packed chains (even j / odd j), step = rot^2
            f16x2 vA = pkrtz(er0f, ei0f);
            f16x2 vB = pkrtz(er1f, ei1f);

            F16x8u ur, ui, un;                     // E1r, E1i, -E1i
#pragma unroll
            for (int jp = 0; jp < 4; ++jp) {
                ur.h[jp] = __builtin_shufflevector(vA, vB, 0, 2);
                const f16x2 hi = __builtin_shufflevector(vA, vB, 1, 3);
                ui.h[jp] = hi;
                un.h[jp] = -hi;
                if (jp < 3) {
                    vA = pkrot(vA, cc2, ns2);
                    vB = pkrot(vB, cc2, ns2);
                }
            }
#pragma unroll
            for (int nt = 0; nt < 4; ++nt) {
                Gr[nt] = __builtin_amdgcn_mfma_f32_16x16x32_f16(Ar[nt][kt], ur.v, Gr[nt], 0, 0, 0);
                Gr[nt] = __builtin_amdgcn_mfma_f32_16x16x32_f16(Ai[nt][kt], un.v, Gr[nt], 0, 0, 0);
                Gi[nt] = __builtin_amdgcn_mfma_f32_16x16x32_f16(Ar[nt][kt], ui.v, Gi[nt], 0, 0, 0);
                Gi[nt] = __builtin_amdgcn_mfma_f32_16x16x32_f16(Ai[nt][kt], ur.v, Gi[nt], 0, 0, 0);
            }
        }

        // ---- stage B: red = Re sum_m G[p,m] e^{2pi i x2 f(m)} ----
        // E2 phases tracked as packed f16, applied via v_dot2_f32_f16.
        const float cs2 = cos1_hw(xv.y);
        const float sn2 = sin1_hw(xv.y);
        float t16 = xv.y * 16.0f;
        t16 -= floorf(t16);
        const float c16 = cos1_hw(t16);
        const float s16 = sin1_hw(t16);
        const float cm32 = fmaf(c16, c16, -(s16 * s16));   // conj(rot16^2)
        const float sm32 = -2.0f * c16 * s16;

        float thA = xv.y * (float)(quad << 2);
        thA -= floorf(thA);
        const float erA = cos1_hw(thA);
        const float eiA = sin1_hw(thA);

        const f16x2 ccs  = pkrtz(cs2, cs2);
        const f16x2 nss  = pkrtz(-sn2, sn2);
        const f16x2 c16p = pkrtz(c16, c16);
        const f16x2 s16n = pkrtz(-s16, s16);
        const f16x2 cm32p = pkrtz(cm32, cm32);
        const f16x2 sm32n = pkrtz(-sm32, sm32);

        const f16x2 b0 = pkrtz(erA, eiA);
        const f16x2 b1 = pkrot(b0, c16p, s16n);
        const f16x2 b2 = pkrot(b0, cm32p, sm32n);   // f jumps -64 at m=32
        const f16x2 b3 = pkrot(b2, c16p, s16n);

        float red = 0.0f;
#pragma unroll
        for (int nt = 0; nt < 4; ++nt) {
            f16x2 w = (nt == 0) ? b0 : (nt == 1) ? b1 : (nt == 2) ? b2 : b3;
#pragma unroll
            for (int reg = 0; reg < 4; ++reg) {
                // red += Gr*er - Gi*ei
                red = fdot2(w, pkrtz(Gr[nt][reg], -Gi[nt][reg]), red);
                if (reg < 3) w = pkrot(w, ccs, nss);
            }
        }
        red += __shfl_xor(red, 16, 64);
        red += __shfl_xor(red, 32, 64);
        if (lane < 16)
            out[pbase + lpt + lane] = red * (1.0f / 4096.0f);
    }
}

extern "C" void kernel_launch(void* const* d_in, const int* in_sizes, int n_in,
                              void* d_out, int out_size, void* d_ws, size_t ws_size,
                              hipStream_t stream)
{
    const float* y    = (const float*)d_in[0];   // [32, 64, 64]
    const float* xnew = (const float*)d_in[1];   // [32, 128, 128, 2]
    float* out        = (float*)d_out;           // [32, 128, 128]

    // ONE dispatch: 32 batches x 8 segment-groups = 256 blocks = 1 per CU.
    fourier_fused<<<256, 1024, 0, stream>>>(y, xnew, out);
}